// Round 13
// baseline (287.723 us; speedup 1.0000x reference)
//
#include <hip/hip_runtime.h>
#include <hip/hip_bf16.h>
#include <math.h>

// Problem constants (from setup_inputs)
#define BB 8
#define QN 512
#define SN 64
#define TN 128
#define DD 128
#define STAT_K 8
#define TOK_K 16
#define SCALE 0.08838834764831845f   // 1/sqrt(128)
#define NEGBIG -1e6f
#define NINF  -3.4e38f

typedef float f4 __attribute__((ext_vector_type(4)));
typedef float f2 __attribute__((ext_vector_type(2)));
typedef unsigned long long u64;

// ---------------------------------------------------------------------------
// LDS-free GEMM tile, 4 rows/thread (64-row blocks, 256 threads, acc[4][8]).
// W read from L1/L2 (broadcast, 64 KB, cache-resident). ~60-70 VGPR, no spill.
// R11-proven: best point of the {8,4,2}-row family (80 us for proj_all).
// transposed: rows are token-rows of [512 bins x 128 tokens]; a 64-row tile
// sits wholly inside one bin -> Cb = C + (rowBase>>7)<<14, col-major store.
// ---------------------------------------------------------------------------
__device__ __forceinline__ void proj_tile4_g(const float* __restrict__ A,
                                             const float* __restrict__ W,
                                             float* __restrict__ C,
                                             int rowBase, int transposed, int tid)
{
    const int tx = tid & 15;    // cols tx*4..+3 and 64+tx*4..+3
    const int ty = tid >> 4;    // 0..15, rows ty*4..+3
    const float* Ab = A + (size_t)(rowBase + ty * 4) * 128;

    float acc[4][8];
    #pragma unroll
    for (int i = 0; i < 4; ++i)
        #pragma unroll
        for (int j = 0; j < 8; ++j) acc[i][j] = 0.f;

    #pragma unroll 2
    for (int k0 = 0; k0 < 128; k0 += 4) {
        f4 a[4];
        #pragma unroll
        for (int i = 0; i < 4; ++i)
            a[i] = *(const f4*)(Ab + i * 128 + k0);        // 16-lane broadcast
        f4 wl[4], wh[4];
        #pragma unroll
        for (int kk = 0; kk < 4; ++kk) {
            wl[kk] = *(const f4*)(W + (size_t)(k0 + kk) * 128 + tx * 4);
            wh[kk] = *(const f4*)(W + (size_t)(k0 + kk) * 128 + 64 + tx * 4);
        }
        #pragma unroll
        for (int i = 0; i < 4; ++i)
            #pragma unroll
            for (int kk = 0; kk < 4; ++kk)
                #pragma unroll
                for (int j = 0; j < 4; ++j) {
                    acc[i][j]     = fmaf(a[i][kk], wl[kk][j], acc[i][j]);
                    acc[i][4 + j] = fmaf(a[i][kk], wh[kk][j], acc[i][4 + j]);
                }
    }

    if (!transposed) {
        #pragma unroll
        for (int i = 0; i < 4; ++i) {
            size_t row = (size_t)rowBase + ty * 4 + i;
            f4 lo = {acc[i][0], acc[i][1], acc[i][2], acc[i][3]};
            f4 hi = {acc[i][4], acc[i][5], acc[i][6], acc[i][7]};
            *(f4*)&C[row * 128 + tx * 4]      = lo;
            *(f4*)&C[row * 128 + 64 + tx * 4] = hi;
        }
    } else {
        float* Cb = C + ((size_t)(rowBase >> 7) << 14);    // bin base
        const int rb = (rowBase & 127) + ty * 4;           // row within bin
        #pragma unroll
        for (int j = 0; j < 4; ++j) {
            int clo = tx * 4 + j;
            int chi = 64 + tx * 4 + j;
            f4 v0 = {acc[0][j], acc[1][j], acc[2][j], acc[3][j]};
            f4 v1 = {acc[0][4 + j], acc[1][4 + j], acc[2][4 + j], acc[3][4 + j]};
            *(f4*)&Cb[clo * 128 + rb] = v0;
            *(f4*)&Cb[chi * 128 + rb] = v1;
        }
    }
}

// Input projections + Wv@Wo fold + cnt zeroing, one launch, 64-row tiles.
// values projection is GONE: PV runs on raw values; out-proj uses M_vo=Wv@Wo.
__global__ __launch_bounds__(256) void proj_all(const float* __restrict__ queries,
                                                const float* __restrict__ stat_keys,
                                                const float* __restrict__ token_keys,
                                                const float* __restrict__ Wq_stat,
                                                const float* __restrict__ Wq_token,
                                                const float* __restrict__ Wk_stat,
                                                const float* __restrict__ Wk_token,
                                                const float* __restrict__ Wv,
                                                const float* __restrict__ Wo,
                                                float* __restrict__ q_stat,
                                                float* __restrict__ q_tok,
                                                float* __restrict__ k_stat,
                                                float* __restrict__ kT,
                                                float* __restrict__ M_vo,
                                                int* __restrict__ cnt)
{
    const int bi = blockIdx.x;
    if (bi < 1024)       proj_tile4_g(token_keys, Wk_token, kT,     bi * 64,           1, threadIdx.x);
    else if (bi < 1088)  proj_tile4_g(queries,    Wq_stat,  q_stat, (bi - 1024) * 64,  0, threadIdx.x);
    else if (bi < 1152)  proj_tile4_g(queries,    Wq_token, q_tok,  (bi - 1088) * 64,  0, threadIdx.x);
    else if (bi < 1160)  proj_tile4_g(stat_keys,  Wk_stat,  k_stat, (bi - 1152) * 64,  0, threadIdx.x);
    else if (bi < 1162)  proj_tile4_g(Wv,         Wo,       M_vo,   (bi - 1160) * 64,  0, threadIdx.x);
    else {
        for (int i = threadIdx.x; i < BB * SN; i += 256) cnt[i] = 0;
    }
}

// Output projection: out = out_pre @ M_vo. 64 rows/block.
__global__ __launch_bounds__(256) void proj_out(const float* __restrict__ A,
                                                const float* __restrict__ W,
                                                float* __restrict__ C)
{
    proj_tile4_g(A, W, C, blockIdx.x * 64, 0, threadIdx.x);
}

// ---------------------------------------------------------------------------
// Stat level + binning fused: one wave per (b,q), lane = stat s. Top-8 +
// softmax (exact jax tie-break). Invalid stats -> exp underflows to exactly 0.
// The 8 selection lanes append (q,si) to their stat's bin (distinct s per
// lane -> no intra-wave atomic contention). Downstream is order-independent.
// ---------------------------------------------------------------------------
__global__ __launch_bounds__(64, 4) void stat_topk(const float* __restrict__ qs,
                                                   const float* __restrict__ ks,
                                                   const int* __restrict__ vlen,
                                                   int* __restrict__ sel_i,
                                                   float* __restrict__ sel_w,
                                                   int* __restrict__ cnt,
                                                   int* __restrict__ list)
{
    const int bq   = blockIdx.x;
    const int b    = bq >> 9;
    const int lane = threadIdx.x;

    const f4* q4 = (const f4*)(qs + (size_t)bq * 128);
    const f4* k4 = (const f4*)(ks + (size_t)(b * SN + lane) * 128);
    float acc = 0.f;
    #pragma unroll 8
    for (int kk = 0; kk < 32; ++kk) {
        f4 q = q4[kk];
        f4 k = k4[kk];
        acc = fmaf(q[0], k[0], acc);
        acc = fmaf(q[1], k[1], acc);
        acc = fmaf(q[2], k[2], acc);
        acc = fmaf(q[3], k[3], acc);
    }
    float score = acc * SCALE;
    if (lane >= vlen[b]) score = NEGBIG;

    float work = score;
    float tv[STAT_K];
    int   ti[STAT_K];
    #pragma unroll
    for (int j = 0; j < STAT_K; ++j) {
        float m = work;
        #pragma unroll
        for (int off = 32; off > 0; off >>= 1) m = fmaxf(m, __shfl_xor(m, off));
        unsigned long long ball = __ballot(work == m);
        int L = __ffsll(ball) - 1;     // lowest index wins ties
        tv[j] = m;
        ti[j] = L;
        if (lane == L) work = NINF;
    }

    float w[STAT_K];
    float Z = 0.f;
    #pragma unroll
    for (int j = 0; j < STAT_K; ++j) { w[j] = expf(tv[j] - tv[0]); Z += w[j]; }
    float invZ = 1.f / Z;

    if (lane < STAT_K) {
        float wv = w[lane] * invZ;
        sel_i[(size_t)bq * STAT_K + lane] = ti[lane];
        sel_w[(size_t)bq * STAT_K + lane] = wv;
        if (wv != 0.f) {                         // sw==0: exactly-zero contribution
            int s  = ti[lane];
            int bs = b * SN + s;
            int pos = atomicAdd(&cnt[bs], 1);
            list[bs * 512 + pos] = (bq & 511) | (lane << 16);
        }
    }
}

// ---------------------------------------------------------------------------
// K1: token scores as a plain GEMM, t-split for occupancy: block =
// (bin, 64-pair chunk, t-half). acc[4][4] = 16 regs, ~70 VGPR, no spill.
// scores[pid][thal*64 + t'] = q_tok[bq] . kT[bs][.][thal*64+t'] * SCALE
// ---------------------------------------------------------------------------
__global__ __launch_bounds__(256) void tok_score(const float* __restrict__ qt,
                                                 const float* __restrict__ kT,
                                                 const int* __restrict__ cnt,
                                                 const int* __restrict__ list,
                                                 float* __restrict__ scores)
{
    const int bin  = blockIdx.x & 511;
    const int rest = blockIdx.x >> 9;  // 0..15
    const int chunk = rest >> 1;
    const int thal  = rest & 1;
    const int b  = bin & 7;            // batch fast -> XCD spread
    const int s  = bin >> 3;
    const int bs = b * SN + s;
    const int nq = cnt[bs];
    const int q0 = chunk * 64;
    if (q0 >= nq) return;

    const int tid = threadIdx.x;
    const int tx = tid & 15;           // t-cols (within half) tx*4..+3
    const int ty = tid >> 4;           // pair-slots q0+ty*4..+3

    int pid[4];
    const float* Ab[4];
    #pragma unroll
    for (int i = 0; i < 4; ++i) {
        int e  = list[bs * 512 + min(q0 + ty * 4 + i, nq - 1)];  // clamp: dup pair
        int q  = e & 0xffff;
        int si = (e >> 16) & 7;
        pid[i] = ((b << 9) + q) * 8 + si;
        Ab[i]  = qt + ((size_t)(b << 9) + q) * 128;
    }
    const float* kb = kT + ((size_t)bs << 14) + thal * 64;

    float acc[4][4];
    #pragma unroll
    for (int i = 0; i < 4; ++i)
        #pragma unroll
        for (int j = 0; j < 4; ++j) acc[i][j] = 0.f;

    #pragma unroll 2
    for (int k0 = 0; k0 < 128; k0 += 4) {
        f4 a[4];
        #pragma unroll
        for (int i = 0; i < 4; ++i)
            a[i] = *(const f4*)(Ab[i] + k0);               // 16-lane broadcast
        f4 wl[4];
        #pragma unroll
        for (int kk = 0; kk < 4; ++kk)
            wl[kk] = *(const f4*)(kb + (size_t)(k0 + kk) * 128 + tx * 4);
        #pragma unroll
        for (int i = 0; i < 4; ++i)
            #pragma unroll
            for (int kk = 0; kk < 4; ++kk)
                #pragma unroll
                for (int j = 0; j < 4; ++j)
                    acc[i][j] = fmaf(a[i][kk], wl[kk][j], acc[i][j]);
    }

    #pragma unroll
    for (int i = 0; i < 4; ++i) {
        f4 o = {acc[i][0] * SCALE, acc[i][1] * SCALE, acc[i][2] * SCALE, acc[i][3] * SCALE};
        *(f4*)(scores + (size_t)pid[i] * 128 + thal * 64 + tx * 4) = o;  // dup pids: identical data
    }
}

// ---------------------------------------------------------------------------
// K2: exact top-16 + softmax weights per pair. ONE THREAD per pid:
// branch-free fully-unrolled 16-deep insertion network over the 128-score
// row (static indices -> registers, no scratch; no cross-lane ops at all).
// Strict > on ascending t == exact jax tie-break (lowest index wins).
// 32768 threads = 512 waves total, ~10k VALU inst each.
// ---------------------------------------------------------------------------
__global__ __launch_bounds__(256) void tok_select(const float* __restrict__ scores,
                                                  const float* __restrict__ sel_w,
                                                  int* __restrict__ pvt,
                                                  float* __restrict__ pvw)
{
    const int pid = blockIdx.x * 256 + threadIdx.x;
    if (pid >= BB * QN * STAT_K) return;

    float sw = sel_w[pid];
    if (sw == 0.f) {                        // never binned: zero contribution
        #pragma unroll
        for (int j = 0; j < TOK_K; ++j) {
            pvt[(size_t)pid * TOK_K + j] = 0;
            pvw[(size_t)pid * TOK_K + j] = 0.f;
        }
        return;
    }

    const f4* row = (const f4*)(scores + (size_t)pid * 128);

    float tv[TOK_K];
    int   ti[TOK_K];
    #pragma unroll
    for (int j = 0; j < TOK_K; ++j) { tv[j] = NINF; ti[j] = 0; }

    #pragma unroll 4
    for (int c = 0; c < 32; ++c) {
        f4 v = row[c];
        #pragma unroll
        for (int e = 0; e < 4; ++e) {
            float x = v[e];
            int  xi = c * 4 + e;
            #pragma unroll
            for (int j = 0; j < TOK_K; ++j) {
                bool s_ = x > tv[j];            // strict: earlier index stays ahead
                float vn = s_ ? x : tv[j];
                float vo = s_ ? tv[j] : x;
                int   in_ = s_ ? xi : ti[j];
                int   io  = s_ ? ti[j] : xi;
                tv[j] = vn; x = vo;
                ti[j] = in_; xi = io;
            }
        }
    }

    float m0 = tv[0];
    float Z = 0.f;
    float pw[TOK_K];
    #pragma unroll
    for (int j = 0; j < TOK_K; ++j) { pw[j] = expf(tv[j] - m0); Z += pw[j]; }
    float cs = sw / Z;                      // fold stat weight in

    #pragma unroll
    for (int j = 0; j < TOK_K; ++j) {
        pvt[(size_t)pid * TOK_K + j] = ti[j];
        pvw[(size_t)pid * TOK_K + j] = pw[j] * cs;
    }
}

// ---------------------------------------------------------------------------
// K3: PV accumulate over RAW values (Wv folded into M_vo). One wave per (b,q),
// registers only, single plain store (no atomics -> deterministic).
// ---------------------------------------------------------------------------
__global__ __launch_bounds__(256) void tok_pv2(const float* __restrict__ values,
                                               const int* __restrict__ sel_i,
                                               const int* __restrict__ pvt,
                                               const float* __restrict__ pvw,
                                               float* __restrict__ out_pre)
{
    const int bq   = blockIdx.x * 4 + (threadIdx.x >> 6);
    const int lane = threadIdx.x & 63;
    const int b    = bq >> 9;

    float o0 = 0.f, o1 = 0.f;
    #pragma unroll
    for (int si = 0; si < STAT_K; ++si) {
        const int pid = bq * STAT_K + si;
        const int s   = sel_i[pid];
        const float* vb = values + ((size_t)(b * SN + s) << 14);
        const int*   tp = pvt + (size_t)pid * TOK_K;
        const float* wp = pvw + (size_t)pid * TOK_K;
        #pragma unroll
        for (int j = 0; j < TOK_K; ++j) {
            int   t = tp[j];                 // wave-uniform
            float w = wp[j];                 // ==0 for skipped pids: exact no-op
            f2 x = *(const f2*)(vb + (size_t)t * 128 + lane * 2);
            o0 = fmaf(w, x[0], o0);
            o1 = fmaf(w, x[1], o1);
        }
    }
    f2 o = {o0, o1};
    *(f2*)(out_pre + (size_t)bq * 128 + lane * 2) = o;
}

// ---------------------------------------------------------------------------
extern "C" void kernel_launch(void* const* d_in, const int* in_sizes, int n_in,
                              void* d_out, int out_size, void* d_ws, size_t ws_size,
                              hipStream_t stream)
{
    const float* queries    = (const float*)d_in[0];
    const float* stat_keys  = (const float*)d_in[1];
    const float* token_keys = (const float*)d_in[2];
    const float* values     = (const float*)d_in[3];
    const int*   vlen       = (const int*)d_in[4];
    const float* Wq_stat    = (const float*)d_in[5];
    const float* Wq_token   = (const float*)d_in[6];
    const float* Wk_stat    = (const float*)d_in[7];
    const float* Wk_token   = (const float*)d_in[8];
    const float* Wv         = (const float*)d_in[9];
    const float* Wo         = (const float*)d_in[10];

    char* ws = (char*)d_ws;
    float* q_stat  = (float*)(ws);                 // 2 MB
    float* q_tok   = (float*)(ws + 2097152);       // 2 MB
    float* k_stat  = (float*)(ws + 4194304);       // 256 KB
    float* M_vo    = (float*)(ws + 4456448);       // 64 KB (Wv @ Wo)
    int*   sel_i   = (int*)  (ws + 4521984);       // 128 KB
    float* sel_w   = (float*)(ws + 4653056);       // 128 KB
    float* kT      = (float*)(ws + 4784128);       // 32 MB
    float* scores  = (float*)(ws + 38338560);      // 16 MB
    int*   pvt     = (int*)  (ws + 55115776);      // 2 MB
    float* pvw     = (float*)(ws + 57212928);      // 2 MB
    float* out_pre = (float*)(ws + 59310080);      // 2 MB
    int*   list    = (int*)  (ws + 61407232);      // 1 MB
    int*   cnt     = (int*)  (ws + 62455808);      // 2 KB   (total ~62.5 MB)

    // Projections feeding selection (fp32 exact) + Wv@Wo fold + cnt zeroing
    proj_all<<<1163, 256, 0, stream>>>(queries, stat_keys, token_keys,
                                       Wq_stat, Wq_token, Wk_stat, Wk_token, Wv, Wo,
                                       q_stat, q_tok, k_stat, kT, M_vo, cnt);

    // Stat-level top-8 selection + weights + bin append (fused)
    stat_topk<<<BB * QN, 64, 0, stream>>>(q_stat, k_stat, vlen, sel_i, sel_w, cnt, list);

    // K1: token scores (GEMM shape, t-split, k read from L2/L3)
    tok_score<<<8192, 256, 0, stream>>>(q_tok, kT, cnt, list, scores);

    // K2: exact top-16 + folded softmax weights, one THREAD per pid
    tok_select<<<BB * QN * STAT_K / 256, 256, 0, stream>>>(scores, sel_w, pvt, pvw);

    // K3: PV accumulate on RAW values, one wave per (b,q), no atomics
    tok_pv2<<<BB * QN / 4, 256, 0, stream>>>(values, sel_i, pvt, pvw, out_pre);

    // Output projection with folded M_vo
    proj_out<<<64, 256, 0, stream>>>(out_pre, M_vo, (float*)d_out);
}

// Round 14
// 245.687 us; speedup vs baseline: 1.1711x; 1.1711x over previous
//
#include <hip/hip_runtime.h>
#include <hip/hip_bf16.h>
#include <math.h>

// Problem constants (from setup_inputs)
#define BB 8
#define QN 512
#define SN 64
#define TN 128
#define DD 128
#define STAT_K 8
#define TOK_K 16
#define SCALE 0.08838834764831845f   // 1/sqrt(128)
#define NEGBIG -1e6f
#define NINF  -3.4e38f

typedef float f4 __attribute__((ext_vector_type(4)));
typedef float f2 __attribute__((ext_vector_type(2)));
typedef unsigned long long u64;

// ---------------------------------------------------------------------------
// LDS-free GEMM tile, 4 rows/thread (64-row blocks, 256 threads, acc[4][8]).
// W read from L1/L2 (broadcast, 64 KB, cache-resident). ~60-70 VGPR, no spill.
// R11-proven best of the {8,4,2}-row family.
// transposed: rows are token-rows of [512 bins x 128 tokens]; a 64-row tile
// sits wholly inside one bin -> Cb = C + (rowBase>>7)<<14, col-major store.
// ---------------------------------------------------------------------------
__device__ __forceinline__ void proj_tile4_g(const float* __restrict__ A,
                                             const float* __restrict__ W,
                                             float* __restrict__ C,
                                             int rowBase, int transposed, int tid)
{
    const int tx = tid & 15;    // cols tx*4..+3 and 64+tx*4..+3
    const int ty = tid >> 4;    // 0..15, rows ty*4..+3
    const float* Ab = A + (size_t)(rowBase + ty * 4) * 128;

    float acc[4][8];
    #pragma unroll
    for (int i = 0; i < 4; ++i)
        #pragma unroll
        for (int j = 0; j < 8; ++j) acc[i][j] = 0.f;

    #pragma unroll 2
    for (int k0 = 0; k0 < 128; k0 += 4) {
        f4 a[4];
        #pragma unroll
        for (int i = 0; i < 4; ++i)
            a[i] = *(const f4*)(Ab + i * 128 + k0);        // 16-lane broadcast
        f4 wl[4], wh[4];
        #pragma unroll
        for (int kk = 0; kk < 4; ++kk) {
            wl[kk] = *(const f4*)(W + (size_t)(k0 + kk) * 128 + tx * 4);
            wh[kk] = *(const f4*)(W + (size_t)(k0 + kk) * 128 + 64 + tx * 4);
        }
        #pragma unroll
        for (int i = 0; i < 4; ++i)
            #pragma unroll
            for (int kk = 0; kk < 4; ++kk)
                #pragma unroll
                for (int j = 0; j < 4; ++j) {
                    acc[i][j]     = fmaf(a[i][kk], wl[kk][j], acc[i][j]);
                    acc[i][4 + j] = fmaf(a[i][kk], wh[kk][j], acc[i][4 + j]);
                }
    }

    if (!transposed) {
        #pragma unroll
        for (int i = 0; i < 4; ++i) {
            size_t row = (size_t)rowBase + ty * 4 + i;
            f4 lo = {acc[i][0], acc[i][1], acc[i][2], acc[i][3]};
            f4 hi = {acc[i][4], acc[i][5], acc[i][6], acc[i][7]};
            *(f4*)&C[row * 128 + tx * 4]      = lo;
            *(f4*)&C[row * 128 + 64 + tx * 4] = hi;
        }
    } else {
        float* Cb = C + ((size_t)(rowBase >> 7) << 14);    // bin base
        const int rb = (rowBase & 127) + ty * 4;           // row within bin
        #pragma unroll
        for (int j = 0; j < 4; ++j) {
            int clo = tx * 4 + j;
            int chi = 64 + tx * 4 + j;
            f4 v0 = {acc[0][j], acc[1][j], acc[2][j], acc[3][j]};
            f4 v1 = {acc[0][4 + j], acc[1][4 + j], acc[2][4 + j], acc[3][4 + j]};
            *(f4*)&Cb[clo * 128 + rb] = v0;
            *(f4*)&Cb[chi * 128 + rb] = v1;
        }
    }
}

// Input projections + Wv@Wo fold + cnt zeroing, one launch, 64-row tiles.
// values projection is GONE: PV runs on raw values; out-proj uses M_vo=Wv@Wo.
__global__ __launch_bounds__(256) void proj_all(const float* __restrict__ queries,
                                                const float* __restrict__ stat_keys,
                                                const float* __restrict__ token_keys,
                                                const float* __restrict__ Wq_stat,
                                                const float* __restrict__ Wq_token,
                                                const float* __restrict__ Wk_stat,
                                                const float* __restrict__ Wk_token,
                                                const float* __restrict__ Wv,
                                                const float* __restrict__ Wo,
                                                float* __restrict__ q_stat,
                                                float* __restrict__ q_tok,
                                                float* __restrict__ k_stat,
                                                float* __restrict__ kT,
                                                float* __restrict__ M_vo,
                                                int* __restrict__ cnt)
{
    const int bi = blockIdx.x;
    if (bi < 1024)       proj_tile4_g(token_keys, Wk_token, kT,     bi * 64,           1, threadIdx.x);
    else if (bi < 1088)  proj_tile4_g(queries,    Wq_stat,  q_stat, (bi - 1024) * 64,  0, threadIdx.x);
    else if (bi < 1152)  proj_tile4_g(queries,    Wq_token, q_tok,  (bi - 1088) * 64,  0, threadIdx.x);
    else if (bi < 1160)  proj_tile4_g(stat_keys,  Wk_stat,  k_stat, (bi - 1152) * 64,  0, threadIdx.x);
    else if (bi < 1162)  proj_tile4_g(Wv,         Wo,       M_vo,   (bi - 1160) * 64,  0, threadIdx.x);
    else {
        for (int i = threadIdx.x; i < BB * SN; i += 256) cnt[i] = 0;
    }
}

// Output projection: out = out_pre @ M_vo. 64 rows/block.
__global__ __launch_bounds__(256) void proj_out(const float* __restrict__ A,
                                                const float* __restrict__ W,
                                                float* __restrict__ C)
{
    proj_tile4_g(A, W, C, blockIdx.x * 64, 0, threadIdx.x);
}

// ---------------------------------------------------------------------------
// Stat level + binning fused: one wave per (b,q), lane = stat s. Top-8 +
// softmax (exact jax tie-break). Invalid stats -> exp underflows to exactly 0.
// Selection lanes append (q,si) to their stat's bin; unbinned (wv==0) pids
// get their pvw row zeroed here (tok_pv2 clamps stale pvt tokens).
// ---------------------------------------------------------------------------
__global__ __launch_bounds__(64, 4) void stat_topk(const float* __restrict__ qs,
                                                   const float* __restrict__ ks,
                                                   const int* __restrict__ vlen,
                                                   int* __restrict__ sel_i,
                                                   float* __restrict__ sel_w,
                                                   int* __restrict__ cnt,
                                                   int* __restrict__ list,
                                                   float* __restrict__ pvw)
{
    const int bq   = blockIdx.x;
    const int b    = bq >> 9;
    const int lane = threadIdx.x;

    const f4* q4 = (const f4*)(qs + (size_t)bq * 128);
    const f4* k4 = (const f4*)(ks + (size_t)(b * SN + lane) * 128);
    float acc = 0.f;
    #pragma unroll 8
    for (int kk = 0; kk < 32; ++kk) {
        f4 q = q4[kk];
        f4 k = k4[kk];
        acc = fmaf(q[0], k[0], acc);
        acc = fmaf(q[1], k[1], acc);
        acc = fmaf(q[2], k[2], acc);
        acc = fmaf(q[3], k[3], acc);
    }
    float score = acc * SCALE;
    if (lane >= vlen[b]) score = NEGBIG;

    float work = score;
    float tv[STAT_K];
    int   ti[STAT_K];
    #pragma unroll
    for (int j = 0; j < STAT_K; ++j) {
        float m = work;
        #pragma unroll
        for (int off = 32; off > 0; off >>= 1) m = fmaxf(m, __shfl_xor(m, off));
        unsigned long long ball = __ballot(work == m);
        int L = __ffsll(ball) - 1;     // lowest index wins ties
        tv[j] = m;
        ti[j] = L;
        if (lane == L) work = NINF;
    }

    float w[STAT_K];
    float Z = 0.f;
    #pragma unroll
    for (int j = 0; j < STAT_K; ++j) { w[j] = expf(tv[j] - tv[0]); Z += w[j]; }
    float invZ = 1.f / Z;

    if (lane < STAT_K) {
        float wv = w[lane] * invZ;
        int pid = bq * STAT_K + lane;
        sel_i[pid] = ti[lane];
        sel_w[pid] = wv;
        if (wv != 0.f) {                         // sw==0: exactly-zero contribution
            int s  = ti[lane];
            int bs = b * SN + s;
            int pos = atomicAdd(&cnt[bs], 1);
            list[bs * 512 + pos] = (bq & 511) | (lane << 16);
        } else {
            #pragma unroll
            for (int j = 0; j < TOK_K; ++j)      // never written downstream: zero
                pvw[(size_t)pid * TOK_K + j] = 0.f;
        }
    }
}

// ---------------------------------------------------------------------------
// K1 (fused): token scores + exact top-16 + softmax weights, all in registers.
// Block = (bin, 64-pair chunk); 16-lane group (fixed ty) holds 4 pids' full
// 128-token score rows in acc[4][8] (t = tx*4+j | 64+tx*4+j-4). Selection:
// 16 iterations of group-max (shfl_xor 1/2/4/8 stays in tx-group) + global
// lowest-t tie-break (exact jax). Lane tx records (t_i, exp) for iteration
// tx; Z = group sum; writes pvt/pvw directly. Scores never touch memory.
// ---------------------------------------------------------------------------
__global__ __launch_bounds__(256) void tok_score_sel(const float* __restrict__ qt,
                                                     const float* __restrict__ kT,
                                                     const int* __restrict__ cnt,
                                                     const int* __restrict__ list,
                                                     const float* __restrict__ sel_w,
                                                     int* __restrict__ pvt,
                                                     float* __restrict__ pvw)
{
    const int bin   = blockIdx.x & 511;
    const int chunk = blockIdx.x >> 9;   // 0..7
    const int b  = bin & 7;              // batch fast -> XCD spread
    const int s  = bin >> 3;
    const int bs = b * SN + s;
    const int nq = cnt[bs];
    const int q0 = chunk * 64;
    if (q0 >= nq) return;                // no barriers in kernel: safe

    const int tid = threadIdx.x;
    const int tx = tid & 15;             // token-cols
    const int ty = tid >> 4;             // pair-slots q0+ty*4..+3

    int pid[4];
    float swp[4];
    const float* Ab[4];
    #pragma unroll
    for (int i = 0; i < 4; ++i) {
        int e  = list[bs * 512 + min(q0 + ty * 4 + i, nq - 1)];  // clamp: dup pair
        int q  = e & 0xffff;
        int si = (e >> 16) & 7;
        pid[i] = ((b << 9) + q) * 8 + si;
        swp[i] = sel_w[pid[i]];
        Ab[i]  = qt + ((size_t)(b << 9) + q) * 128;
    }
    const float* kb = kT + ((size_t)bs << 14);

    float acc[4][8];
    #pragma unroll
    for (int i = 0; i < 4; ++i)
        #pragma unroll
        for (int j = 0; j < 8; ++j) acc[i][j] = 0.f;

    #pragma unroll 2
    for (int k0 = 0; k0 < 128; k0 += 4) {
        f4 a[4];
        #pragma unroll
        for (int i = 0; i < 4; ++i)
            a[i] = *(const f4*)(Ab[i] + k0);               // 16-lane broadcast
        f4 wl[4], wh[4];
        #pragma unroll
        for (int kk = 0; kk < 4; ++kk) {
            wl[kk] = *(const f4*)(kb + (size_t)(k0 + kk) * 128 + tx * 4);
            wh[kk] = *(const f4*)(kb + (size_t)(k0 + kk) * 128 + 64 + tx * 4);
        }
        #pragma unroll
        for (int i = 0; i < 4; ++i)
            #pragma unroll
            for (int kk = 0; kk < 4; ++kk)
                #pragma unroll
                for (int j = 0; j < 4; ++j) {
                    acc[i][j]     = fmaf(a[i][kk], wl[kk][j], acc[i][j]);
                    acc[i][4 + j] = fmaf(a[i][kk], wh[kk][j], acc[i][4 + j]);
                }
    }

    // ---- in-register exact top-16 + softmax per pid ----
    #pragma unroll
    for (int i = 0; i < 4; ++i) {
        float s8[8];
        #pragma unroll
        for (int j = 0; j < 8; ++j) s8[j] = acc[i][j] * SCALE;

        float m0 = 0.f;
        int   myT = 0;
        float myE = 0.f;

        for (int it = 0; it < 16; ++it) {
            // group max of remaining scores
            float m = s8[0];
            #pragma unroll
            for (int j = 1; j < 8; ++j) m = fmaxf(m, s8[j]);
            #pragma unroll
            for (int off = 8; off > 0; off >>= 1) m = fmaxf(m, __shfl_xor(m, off));

            // per-lane lowest-t slot holding m (descending-t overwrite scan)
            int tc = 1024, sc = 0;
            #pragma unroll
            for (int j = 7; j >= 4; --j) {
                bool hit = (s8[j] == m);
                tc = hit ? (64 + tx * 4 + (j - 4)) : tc;
                sc = hit ? j : sc;
            }
            #pragma unroll
            for (int j = 3; j >= 0; --j) {
                bool hit = (s8[j] == m);
                tc = hit ? (tx * 4 + j) : tc;
                sc = hit ? j : sc;
            }
            // global lowest t achieving m (exact jax tie-break)
            int tmin = tc;
            #pragma unroll
            for (int off = 8; off > 0; off >>= 1) tmin = min(tmin, __shfl_xor(tmin, off));

            m0 = (it == 0) ? m : m0;
            if (tx == it) { myT = tmin; myE = expf(m - m0); }
            if (tc == tmin) s8[sc] = NINF;     // unique winner knocks its slot
        }

        float Z = myE;
        #pragma unroll
        for (int off = 8; off > 0; off >>= 1) Z += __shfl_xor(Z, off);
        float cs = swp[i] / Z;                 // fold stat weight in

        pvt[(size_t)pid[i] * TOK_K + tx] = myT;   // dup pids: identical data, benign
        pvw[(size_t)pid[i] * TOK_K + tx] = myE * cs;
    }
}

// ---------------------------------------------------------------------------
// K3: PV accumulate over RAW values (Wv folded into M_vo). One wave per (b,q),
// registers only, single plain store (no atomics -> deterministic).
// t clamped to [0,127]: stale pvt for unbinned pids is harmless (pvw==0).
// ---------------------------------------------------------------------------
__global__ __launch_bounds__(256) void tok_pv2(const float* __restrict__ values,
                                               const int* __restrict__ sel_i,
                                               const int* __restrict__ pvt,
                                               const float* __restrict__ pvw,
                                               float* __restrict__ out_pre)
{
    const int bq   = blockIdx.x * 4 + (threadIdx.x >> 6);
    const int lane = threadIdx.x & 63;
    const int b    = bq >> 9;

    float o0 = 0.f, o1 = 0.f;
    #pragma unroll
    for (int si = 0; si < STAT_K; ++si) {
        const int pid = bq * STAT_K + si;
        const int s   = sel_i[pid];
        const float* vb = values + ((size_t)(b * SN + s) << 14);
        const int*   tp = pvt + (size_t)pid * TOK_K;
        const float* wp = pvw + (size_t)pid * TOK_K;
        #pragma unroll
        for (int j = 0; j < TOK_K; ++j) {
            int   t = tp[j] & 127;           // wave-uniform; clamp stale entries
            float w = wp[j];                 // ==0 for skipped pids: exact no-op
            f2 x = *(const f2*)(vb + (size_t)t * 128 + lane * 2);
            o0 = fmaf(w, x[0], o0);
            o1 = fmaf(w, x[1], o1);
        }
    }
    f2 o = {o0, o1};
    *(f2*)(out_pre + (size_t)bq * 128 + lane * 2) = o;
}

// ---------------------------------------------------------------------------
extern "C" void kernel_launch(void* const* d_in, const int* in_sizes, int n_in,
                              void* d_out, int out_size, void* d_ws, size_t ws_size,
                              hipStream_t stream)
{
    const float* queries    = (const float*)d_in[0];
    const float* stat_keys  = (const float*)d_in[1];
    const float* token_keys = (const float*)d_in[2];
    const float* values     = (const float*)d_in[3];
    const int*   vlen       = (const int*)d_in[4];
    const float* Wq_stat    = (const float*)d_in[5];
    const float* Wq_token   = (const float*)d_in[6];
    const float* Wk_stat    = (const float*)d_in[7];
    const float* Wk_token   = (const float*)d_in[8];
    const float* Wv         = (const float*)d_in[9];
    const float* Wo         = (const float*)d_in[10];

    char* ws = (char*)d_ws;
    float* q_stat  = (float*)(ws);                 // 2 MB
    float* q_tok   = (float*)(ws + 2097152);       // 2 MB
    float* k_stat  = (float*)(ws + 4194304);       // 256 KB
    float* M_vo    = (float*)(ws + 4456448);       // 64 KB (Wv @ Wo)
    int*   sel_i   = (int*)  (ws + 4521984);       // 128 KB
    float* sel_w   = (float*)(ws + 4653056);       // 128 KB
    float* kT      = (float*)(ws + 4784128);       // 32 MB
    int*   pvt     = (int*)  (ws + 38338560);      // 2 MB
    float* pvw     = (float*)(ws + 40435712);      // 2 MB
    float* out_pre = (float*)(ws + 42532864);      // 2 MB
    int*   list    = (int*)  (ws + 44630016);      // 1 MB
    int*   cnt     = (int*)  (ws + 45678592);      // 2 KB   (total ~45.7 MB)

    // Projections feeding selection (fp32 exact) + Wv@Wo fold + cnt zeroing
    proj_all<<<1163, 256, 0, stream>>>(queries, stat_keys, token_keys,
                                       Wq_stat, Wq_token, Wk_stat, Wk_token, Wv, Wo,
                                       q_stat, q_tok, k_stat, kT, M_vo, cnt);

    // Stat-level top-8 + weights + bin append + pvw zeroing (fused)
    stat_topk<<<BB * QN, 64, 0, stream>>>(q_stat, k_stat, vlen, sel_i, sel_w,
                                          cnt, list, pvw);

    // K1: token scores + in-register top-16 + weights (fused; no scores buffer)
    tok_score_sel<<<4096, 256, 0, stream>>>(q_tok, kT, cnt, list, sel_w, pvt, pvw);

    // K3: PV accumulate on RAW values, one wave per (b,q), no atomics
    tok_pv2<<<BB * QN / 4, 256, 0, stream>>>(values, sel_i, pvt, pvw, out_pre);

    // Output projection with folded M_vo
    proj_out<<<64, 256, 0, stream>>>(out_pre, M_vo, (float*)d_out);
}

// Round 15
// 236.251 us; speedup vs baseline: 1.2179x; 1.0399x over previous
//
#include <hip/hip_runtime.h>
#include <hip/hip_bf16.h>
#include <math.h>

// Problem constants (from setup_inputs)
#define BB 8
#define QN 512
#define SN 64
#define TN 128
#define DD 128
#define STAT_K 8
#define TOK_K 16
#define SCALE 0.08838834764831845f   // 1/sqrt(128)
#define NEGBIG -1e6f
#define NINF  -3.4e38f

typedef float f4 __attribute__((ext_vector_type(4)));
typedef float f2 __attribute__((ext_vector_type(2)));
typedef unsigned long long u64;

// ---------------------------------------------------------------------------
// LDS-free GEMM tile, 4 rows/thread (64-row blocks, 256 threads, acc[4][8]).
// W read from L1/L2 (broadcast, 64 KB, cache-resident). ~60-70 VGPR, no spill.
// R11-proven best of the {8,4,2}-row family.
// transposed: rows are token-rows of [512 bins x 128 tokens]; a 64-row tile
// sits wholly inside one bin -> Cb = C + (rowBase>>7)<<14, col-major store.
// ---------------------------------------------------------------------------
__device__ __forceinline__ void proj_tile4_g(const float* __restrict__ A,
                                             const float* __restrict__ W,
                                             float* __restrict__ C,
                                             int rowBase, int transposed, int tid)
{
    const int tx = tid & 15;    // cols tx*4..+3 and 64+tx*4..+3
    const int ty = tid >> 4;    // 0..15, rows ty*4..+3
    const float* Ab = A + (size_t)(rowBase + ty * 4) * 128;

    float acc[4][8];
    #pragma unroll
    for (int i = 0; i < 4; ++i)
        #pragma unroll
        for (int j = 0; j < 8; ++j) acc[i][j] = 0.f;

    #pragma unroll 2
    for (int k0 = 0; k0 < 128; k0 += 4) {
        f4 a[4];
        #pragma unroll
        for (int i = 0; i < 4; ++i)
            a[i] = *(const f4*)(Ab + i * 128 + k0);        // 16-lane broadcast
        f4 wl[4], wh[4];
        #pragma unroll
        for (int kk = 0; kk < 4; ++kk) {
            wl[kk] = *(const f4*)(W + (size_t)(k0 + kk) * 128 + tx * 4);
            wh[kk] = *(const f4*)(W + (size_t)(k0 + kk) * 128 + 64 + tx * 4);
        }
        #pragma unroll
        for (int i = 0; i < 4; ++i)
            #pragma unroll
            for (int kk = 0; kk < 4; ++kk)
                #pragma unroll
                for (int j = 0; j < 4; ++j) {
                    acc[i][j]     = fmaf(a[i][kk], wl[kk][j], acc[i][j]);
                    acc[i][4 + j] = fmaf(a[i][kk], wh[kk][j], acc[i][4 + j]);
                }
    }

    if (!transposed) {
        #pragma unroll
        for (int i = 0; i < 4; ++i) {
            size_t row = (size_t)rowBase + ty * 4 + i;
            f4 lo = {acc[i][0], acc[i][1], acc[i][2], acc[i][3]};
            f4 hi = {acc[i][4], acc[i][5], acc[i][6], acc[i][7]};
            *(f4*)&C[row * 128 + tx * 4]      = lo;
            *(f4*)&C[row * 128 + 64 + tx * 4] = hi;
        }
    } else {
        float* Cb = C + ((size_t)(rowBase >> 7) << 14);    // bin base
        const int rb = (rowBase & 127) + ty * 4;           // row within bin
        #pragma unroll
        for (int j = 0; j < 4; ++j) {
            int clo = tx * 4 + j;
            int chi = 64 + tx * 4 + j;
            f4 v0 = {acc[0][j], acc[1][j], acc[2][j], acc[3][j]};
            f4 v1 = {acc[0][4 + j], acc[1][4 + j], acc[2][4 + j], acc[3][4 + j]};
            *(f4*)&Cb[clo * 128 + rb] = v0;
            *(f4*)&Cb[chi * 128 + rb] = v1;
        }
    }
}

// Input projections + Wv@Wo fold + cnt zeroing, one launch, 64-row tiles.
// values projection is GONE: PV runs on raw values; out-proj uses M_vo=Wv@Wo.
__global__ __launch_bounds__(256) void proj_all(const float* __restrict__ queries,
                                                const float* __restrict__ stat_keys,
                                                const float* __restrict__ token_keys,
                                                const float* __restrict__ Wq_stat,
                                                const float* __restrict__ Wq_token,
                                                const float* __restrict__ Wk_stat,
                                                const float* __restrict__ Wk_token,
                                                const float* __restrict__ Wv,
                                                const float* __restrict__ Wo,
                                                float* __restrict__ q_stat,
                                                float* __restrict__ q_tok,
                                                float* __restrict__ k_stat,
                                                float* __restrict__ kT,
                                                float* __restrict__ M_vo,
                                                int* __restrict__ cnt)
{
    const int bi = blockIdx.x;
    if (bi < 1024)       proj_tile4_g(token_keys, Wk_token, kT,     bi * 64,           1, threadIdx.x);
    else if (bi < 1088)  proj_tile4_g(queries,    Wq_stat,  q_stat, (bi - 1024) * 64,  0, threadIdx.x);
    else if (bi < 1152)  proj_tile4_g(queries,    Wq_token, q_tok,  (bi - 1088) * 64,  0, threadIdx.x);
    else if (bi < 1160)  proj_tile4_g(stat_keys,  Wk_stat,  k_stat, (bi - 1152) * 64,  0, threadIdx.x);
    else if (bi < 1162)  proj_tile4_g(Wv,         Wo,       M_vo,   (bi - 1160) * 64,  0, threadIdx.x);
    else {
        for (int i = threadIdx.x; i < BB * SN; i += 256) cnt[i] = 0;
    }
}

// Output projection: out = out_pre @ M_vo. 64 rows/block.
__global__ __launch_bounds__(256) void proj_out(const float* __restrict__ A,
                                                const float* __restrict__ W,
                                                float* __restrict__ C)
{
    proj_tile4_g(A, W, C, blockIdx.x * 64, 0, threadIdx.x);
}

// ---------------------------------------------------------------------------
// Stat level + binning fused: one wave per (b,q), lane = stat s. Top-8 +
// softmax (exact jax tie-break). Invalid stats -> exp underflows to exactly 0.
// Selection lanes append (q,si) to their stat's bin; unbinned (wv==0) pids
// get their pvw row zeroed here (tok_pv2 clamps stale pvt tokens).
// ---------------------------------------------------------------------------
__global__ __launch_bounds__(64, 4) void stat_topk(const float* __restrict__ qs,
                                                   const float* __restrict__ ks,
                                                   const int* __restrict__ vlen,
                                                   int* __restrict__ sel_i,
                                                   float* __restrict__ sel_w,
                                                   int* __restrict__ cnt,
                                                   int* __restrict__ list,
                                                   float* __restrict__ pvw)
{
    const int bq   = blockIdx.x;
    const int b    = bq >> 9;
    const int lane = threadIdx.x;

    const f4* q4 = (const f4*)(qs + (size_t)bq * 128);
    const f4* k4 = (const f4*)(ks + (size_t)(b * SN + lane) * 128);
    float acc = 0.f;
    #pragma unroll 8
    for (int kk = 0; kk < 32; ++kk) {
        f4 q = q4[kk];
        f4 k = k4[kk];
        acc = fmaf(q[0], k[0], acc);
        acc = fmaf(q[1], k[1], acc);
        acc = fmaf(q[2], k[2], acc);
        acc = fmaf(q[3], k[3], acc);
    }
    float score = acc * SCALE;
    if (lane >= vlen[b]) score = NEGBIG;

    float work = score;
    float tv[STAT_K];
    int   ti[STAT_K];
    #pragma unroll
    for (int j = 0; j < STAT_K; ++j) {
        float m = work;
        #pragma unroll
        for (int off = 32; off > 0; off >>= 1) m = fmaxf(m, __shfl_xor(m, off));
        unsigned long long ball = __ballot(work == m);
        int L = __ffsll(ball) - 1;     // lowest index wins ties
        tv[j] = m;
        ti[j] = L;
        if (lane == L) work = NINF;
    }

    float w[STAT_K];
    float Z = 0.f;
    #pragma unroll
    for (int j = 0; j < STAT_K; ++j) { w[j] = expf(tv[j] - tv[0]); Z += w[j]; }
    float invZ = 1.f / Z;

    if (lane < STAT_K) {
        float wv = w[lane] * invZ;
        int pid = bq * STAT_K + lane;
        sel_i[pid] = ti[lane];
        sel_w[pid] = wv;
        if (wv != 0.f) {                         // sw==0: exactly-zero contribution
            int s  = ti[lane];
            int bs = b * SN + s;
            int pos = atomicAdd(&cnt[bs], 1);
            list[bs * 512 + pos] = (bq & 511) | (lane << 16);
        } else {
            #pragma unroll
            for (int j = 0; j < TOK_K; ++j)      // never written downstream: zero
                pvw[(size_t)pid * TOK_K + j] = 0.f;
        }
    }
}

// ---------------------------------------------------------------------------
// K1 (fused): token scores + exact top-16 + softmax weights, all in registers.
// Block = (bin, 64-pair chunk); 16-lane group (fixed ty) holds 4 pids' full
// 128-token score rows in acc[4][8]. Selection: it-loop OUTER, 4 pids inner
// (unrolled) -> the 4 independent shfl chains interleave (4x ILP on the
// latency-critical cross-lane path; R14 had them sequential). Knock is an
// explicit branch-free 8-way select (no runtime-indexed register writes).
// Exact jax tie-break: group max then global lowest-t. Scores never hit mem.
// ---------------------------------------------------------------------------
__global__ __launch_bounds__(256) void tok_score_sel(const float* __restrict__ qt,
                                                     const float* __restrict__ kT,
                                                     const int* __restrict__ cnt,
                                                     const int* __restrict__ list,
                                                     const float* __restrict__ sel_w,
                                                     int* __restrict__ pvt,
                                                     float* __restrict__ pvw)
{
    const int bin   = blockIdx.x & 511;
    const int chunk = blockIdx.x >> 9;   // 0..7
    const int b  = bin & 7;              // batch fast -> XCD spread
    const int s  = bin >> 3;
    const int bs = b * SN + s;
    const int nq = cnt[bs];
    const int q0 = chunk * 64;
    if (q0 >= nq) return;                // no barriers in kernel: safe

    const int tid = threadIdx.x;
    const int tx = tid & 15;             // token-cols
    const int ty = tid >> 4;             // pair-slots q0+ty*4..+3

    int pid[4];
    float swp[4];
    const float* Ab[4];
    #pragma unroll
    for (int i = 0; i < 4; ++i) {
        int e  = list[bs * 512 + min(q0 + ty * 4 + i, nq - 1)];  // clamp: dup pair
        int q  = e & 0xffff;
        int si = (e >> 16) & 7;
        pid[i] = ((b << 9) + q) * 8 + si;
        swp[i] = sel_w[pid[i]];
        Ab[i]  = qt + ((size_t)(b << 9) + q) * 128;
    }
    const float* kb = kT + ((size_t)bs << 14);

    float acc[4][8];
    #pragma unroll
    for (int i = 0; i < 4; ++i)
        #pragma unroll
        for (int j = 0; j < 8; ++j) acc[i][j] = 0.f;

    #pragma unroll 2
    for (int k0 = 0; k0 < 128; k0 += 4) {
        f4 a[4];
        #pragma unroll
        for (int i = 0; i < 4; ++i)
            a[i] = *(const f4*)(Ab[i] + k0);               // 16-lane broadcast
        f4 wl[4], wh[4];
        #pragma unroll
        for (int kk = 0; kk < 4; ++kk) {
            wl[kk] = *(const f4*)(kb + (size_t)(k0 + kk) * 128 + tx * 4);
            wh[kk] = *(const f4*)(kb + (size_t)(k0 + kk) * 128 + 64 + tx * 4);
        }
        #pragma unroll
        for (int i = 0; i < 4; ++i)
            #pragma unroll
            for (int kk = 0; kk < 4; ++kk)
                #pragma unroll
                for (int j = 0; j < 4; ++j) {
                    acc[i][j]     = fmaf(a[i][kk], wl[kk][j], acc[i][j]);
                    acc[i][4 + j] = fmaf(a[i][kk], wh[kk][j], acc[i][4 + j]);
                }
    }

    // ---- in-register exact top-16 + softmax, 4 pids interleaved ----
    float s8[4][8];
    #pragma unroll
    for (int i = 0; i < 4; ++i)
        #pragma unroll
        for (int j = 0; j < 8; ++j) s8[i][j] = acc[i][j] * SCALE;

    float m0[4];
    int   myT[4];
    float myE[4];
    #pragma unroll
    for (int i = 0; i < 4; ++i) { m0[i] = 0.f; myT[i] = 0; myE[i] = 0.f; }

    for (int it = 0; it < 16; ++it) {
        #pragma unroll
        for (int i = 0; i < 4; ++i) {
            // group max of remaining scores
            float m = s8[i][0];
            #pragma unroll
            for (int j = 1; j < 8; ++j) m = fmaxf(m, s8[i][j]);
            #pragma unroll
            for (int off = 8; off > 0; off >>= 1) m = fmaxf(m, __shfl_xor(m, off));

            // per-lane lowest-t slot holding m (descending scan -> lowest t wins)
            int tc = 1024, sc = 0;
            #pragma unroll
            for (int j = 7; j >= 4; --j) {
                bool hit = (s8[i][j] == m);
                tc = hit ? (64 + tx * 4 + (j - 4)) : tc;
                sc = hit ? j : sc;
            }
            #pragma unroll
            for (int j = 3; j >= 0; --j) {
                bool hit = (s8[i][j] == m);
                tc = hit ? (tx * 4 + j) : tc;
                sc = hit ? j : sc;
            }
            // global lowest t achieving m (exact jax tie-break)
            int tmin = tc;
            #pragma unroll
            for (int off = 8; off > 0; off >>= 1) tmin = min(tmin, __shfl_xor(tmin, off));

            m0[i] = (it == 0) ? m : m0[i];
            if (tx == it) { myT[i] = tmin; myE[i] = expf(m - m0[i]); }

            // branch-free knock of the unique winning slot (static indices)
            bool win = (tc == tmin);
            #pragma unroll
            for (int j = 0; j < 8; ++j)
                s8[i][j] = (win && sc == j) ? NINF : s8[i][j];
        }
    }

    #pragma unroll
    for (int i = 0; i < 4; ++i) {
        float Z = myE[i];
        #pragma unroll
        for (int off = 8; off > 0; off >>= 1) Z += __shfl_xor(Z, off);
        float cs = swp[i] / Z;                 // fold stat weight in

        pvt[(size_t)pid[i] * TOK_K + tx] = myT[i];   // dup pids: identical data
        pvw[(size_t)pid[i] * TOK_K + tx] = myE[i] * cs;
    }
}

// ---------------------------------------------------------------------------
// K3: PV accumulate over RAW values (Wv folded into M_vo). One wave per (b,q),
// registers only, single plain store (no atomics -> deterministic).
// t clamped to [0,127]: stale pvt for unbinned pids is harmless (pvw==0).
// ---------------------------------------------------------------------------
__global__ __launch_bounds__(256) void tok_pv2(const float* __restrict__ values,
                                               const int* __restrict__ sel_i,
                                               const int* __restrict__ pvt,
                                               const float* __restrict__ pvw,
                                               float* __restrict__ out_pre)
{
    const int bq   = blockIdx.x * 4 + (threadIdx.x >> 6);
    const int lane = threadIdx.x & 63;
    const int b    = bq >> 9;

    float o0 = 0.f, o1 = 0.f;
    #pragma unroll
    for (int si = 0; si < STAT_K; ++si) {
        const int pid = bq * STAT_K + si;
        const int s   = sel_i[pid];
        const float* vb = values + ((size_t)(b * SN + s) << 14);
        const int*   tp = pvt + (size_t)pid * TOK_K;
        const float* wp = pvw + (size_t)pid * TOK_K;
        #pragma unroll
        for (int j = 0; j < TOK_K; ++j) {
            int   t = tp[j] & 127;           // wave-uniform; clamp stale entries
            float w = wp[j];                 // ==0 for skipped pids: exact no-op
            f2 x = *(const f2*)(vb + (size_t)t * 128 + lane * 2);
            o0 = fmaf(w, x[0], o0);
            o1 = fmaf(w, x[1], o1);
        }
    }
    f2 o = {o0, o1};
    *(f2*)(out_pre + (size_t)bq * 128 + lane * 2) = o;
}

// ---------------------------------------------------------------------------
extern "C" void kernel_launch(void* const* d_in, const int* in_sizes, int n_in,
                              void* d_out, int out_size, void* d_ws, size_t ws_size,
                              hipStream_t stream)
{
    const float* queries    = (const float*)d_in[0];
    const float* stat_keys  = (const float*)d_in[1];
    const float* token_keys = (const float*)d_in[2];
    const float* values     = (const float*)d_in[3];
    const int*   vlen       = (const int*)d_in[4];
    const float* Wq_stat    = (const float*)d_in[5];
    const float* Wq_token   = (const float*)d_in[6];
    const float* Wk_stat    = (const float*)d_in[7];
    const float* Wk_token   = (const float*)d_in[8];
    const float* Wv         = (const float*)d_in[9];
    const float* Wo         = (const float*)d_in[10];

    char* ws = (char*)d_ws;
    float* q_stat  = (float*)(ws);                 // 2 MB
    float* q_tok   = (float*)(ws + 2097152);       // 2 MB
    float* k_stat  = (float*)(ws + 4194304);       // 256 KB
    float* M_vo    = (float*)(ws + 4456448);       // 64 KB (Wv @ Wo)
    int*   sel_i   = (int*)  (ws + 4521984);       // 128 KB
    float* sel_w   = (float*)(ws + 4653056);       // 128 KB
    float* kT      = (float*)(ws + 4784128);       // 32 MB
    int*   pvt     = (int*)  (ws + 38338560);      // 2 MB
    float* pvw     = (float*)(ws + 40435712);      // 2 MB
    float* out_pre = (float*)(ws + 42532864);      // 2 MB
    int*   list    = (int*)  (ws + 44630016);      // 1 MB
    int*   cnt     = (int*)  (ws + 45678592);      // 2 KB   (total ~45.7 MB)

    // Projections feeding selection (fp32 exact) + Wv@Wo fold + cnt zeroing
    proj_all<<<1163, 256, 0, stream>>>(queries, stat_keys, token_keys,
                                       Wq_stat, Wq_token, Wk_stat, Wk_token, Wv, Wo,
                                       q_stat, q_tok, k_stat, kT, M_vo, cnt);

    // Stat-level top-8 + weights + bin append + pvw zeroing (fused)
    stat_topk<<<BB * QN, 64, 0, stream>>>(q_stat, k_stat, vlen, sel_i, sel_w,
                                          cnt, list, pvw);

    // K1: token scores + in-register top-16 + weights (fused; no scores buffer)
    tok_score_sel<<<4096, 256, 0, stream>>>(q_tok, kT, cnt, list, sel_w, pvt, pvw);

    // K3: PV accumulate on RAW values, one wave per (b,q), no atomics
    tok_pv2<<<BB * QN / 4, 256, 0, stream>>>(values, sel_i, pvt, pvw, out_pre);

    // Output projection with folded M_vo
    proj_out<<<64, 256, 0, stream>>>(out_pre, M_vo, (float*)d_out);
}

// Round 17
// 211.522 us; speedup vs baseline: 1.3603x; 1.1169x over previous
//
#include <hip/hip_runtime.h>
#include <hip/hip_bf16.h>
#include <math.h>

// Problem constants (from setup_inputs)
#define BB 8
#define QN 512
#define SN 64
#define TN 128
#define DD 128
#define STAT_K 8
#define TOK_K 16
#define SCALE 0.08838834764831845f   // 1/sqrt(128)
#define NEGBIG -1e6f
#define NINF  -3.4e38f

typedef float f4 __attribute__((ext_vector_type(4)));
typedef float f2 __attribute__((ext_vector_type(2)));
typedef unsigned long long u64;

// ---------------------------------------------------------------------------
// LDS-free GEMM tile, 4 rows/thread (64-row blocks, 256 threads, acc[4][8]).
// W read from L1/L2 (broadcast, 64 KB, cache-resident). R11-proven.
// transposed: per-bin col-major store (see R11 notes).
// ---------------------------------------------------------------------------
__device__ __forceinline__ void proj_tile4_g(const float* __restrict__ A,
                                             const float* __restrict__ W,
                                             float* __restrict__ C,
                                             int rowBase, int transposed, int tid)
{
    const int tx = tid & 15;    // cols tx*4..+3 and 64+tx*4..+3
    const int ty = tid >> 4;    // 0..15, rows ty*4..+3
    const float* Ab = A + (size_t)(rowBase + ty * 4) * 128;

    float acc[4][8];
    #pragma unroll
    for (int i = 0; i < 4; ++i)
        #pragma unroll
        for (int j = 0; j < 8; ++j) acc[i][j] = 0.f;

    #pragma unroll 2
    for (int k0 = 0; k0 < 128; k0 += 4) {
        f4 a[4];
        #pragma unroll
        for (int i = 0; i < 4; ++i)
            a[i] = *(const f4*)(Ab + i * 128 + k0);        // 16-lane broadcast
        f4 wl[4], wh[4];
        #pragma unroll
        for (int kk = 0; kk < 4; ++kk) {
            wl[kk] = *(const f4*)(W + (size_t)(k0 + kk) * 128 + tx * 4);
            wh[kk] = *(const f4*)(W + (size_t)(k0 + kk) * 128 + 64 + tx * 4);
        }
        #pragma unroll
        for (int i = 0; i < 4; ++i)
            #pragma unroll
            for (int kk = 0; kk < 4; ++kk)
                #pragma unroll
                for (int j = 0; j < 4; ++j) {
                    acc[i][j]     = fmaf(a[i][kk], wl[kk][j], acc[i][j]);
                    acc[i][4 + j] = fmaf(a[i][kk], wh[kk][j], acc[i][4 + j]);
                }
    }

    if (!transposed) {
        #pragma unroll
        for (int i = 0; i < 4; ++i) {
            size_t row = (size_t)rowBase + ty * 4 + i;
            f4 lo = {acc[i][0], acc[i][1], acc[i][2], acc[i][3]};
            f4 hi = {acc[i][4], acc[i][5], acc[i][6], acc[i][7]};
            *(f4*)&C[row * 128 + tx * 4]      = lo;
            *(f4*)&C[row * 128 + 64 + tx * 4] = hi;
        }
    } else {
        float* Cb = C + ((size_t)(rowBase >> 7) << 14);    // bin base
        const int rb = (rowBase & 127) + ty * 4;           // row within bin
        #pragma unroll
        for (int j = 0; j < 4; ++j) {
            int clo = tx * 4 + j;
            int chi = 64 + tx * 4 + j;
            f4 v0 = {acc[0][j], acc[1][j], acc[2][j], acc[3][j]};
            f4 v1 = {acc[0][4 + j], acc[1][4 + j], acc[2][4 + j], acc[3][4 + j]};
            *(f4*)&Cb[clo * 128 + rb] = v0;
            *(f4*)&Cb[chi * 128 + rb] = v1;
        }
    }
}

// Input projections + Wv@Wo fold + cnt zeroing, one launch, 64-row tiles.
__global__ __launch_bounds__(256) void proj_all(const float* __restrict__ queries,
                                                const float* __restrict__ stat_keys,
                                                const float* __restrict__ token_keys,
                                                const float* __restrict__ Wq_stat,
                                                const float* __restrict__ Wq_token,
                                                const float* __restrict__ Wk_stat,
                                                const float* __restrict__ Wk_token,
                                                const float* __restrict__ Wv,
                                                const float* __restrict__ Wo,
                                                float* __restrict__ q_stat,
                                                float* __restrict__ q_tok,
                                                float* __restrict__ k_stat,
                                                float* __restrict__ kT,
                                                float* __restrict__ M_vo,
                                                int* __restrict__ cnt)
{
    const int bi = blockIdx.x;
    if (bi < 1024)       proj_tile4_g(token_keys, Wk_token, kT,     bi * 64,           1, threadIdx.x);
    else if (bi < 1088)  proj_tile4_g(queries,    Wq_stat,  q_stat, (bi - 1024) * 64,  0, threadIdx.x);
    else if (bi < 1152)  proj_tile4_g(queries,    Wq_token, q_tok,  (bi - 1088) * 64,  0, threadIdx.x);
    else if (bi < 1160)  proj_tile4_g(stat_keys,  Wk_stat,  k_stat, (bi - 1152) * 64,  0, threadIdx.x);
    else if (bi < 1162)  proj_tile4_g(Wv,         Wo,       M_vo,   (bi - 1160) * 64,  0, threadIdx.x);
    else {
        for (int i = threadIdx.x; i < BB * SN; i += 256) cnt[i] = 0;
    }
}

// ---------------------------------------------------------------------------
// Stat level + binning fused (R12-proven). Unbinned (wv==0) pids get their
// pvw row zeroed here (tok_pv3 clamps stale pvt tokens).
// ---------------------------------------------------------------------------
__global__ __launch_bounds__(64, 4) void stat_topk(const float* __restrict__ qs,
                                                   const float* __restrict__ ks,
                                                   const int* __restrict__ vlen,
                                                   int* __restrict__ sel_i,
                                                   float* __restrict__ sel_w,
                                                   int* __restrict__ cnt,
                                                   int* __restrict__ list,
                                                   float* __restrict__ pvw)
{
    const int bq   = blockIdx.x;
    const int b    = bq >> 9;
    const int lane = threadIdx.x;

    const f4* q4 = (const f4*)(qs + (size_t)bq * 128);
    const f4* k4 = (const f4*)(ks + (size_t)(b * SN + lane) * 128);
    float acc = 0.f;
    #pragma unroll 8
    for (int kk = 0; kk < 32; ++kk) {
        f4 q = q4[kk];
        f4 k = k4[kk];
        acc = fmaf(q[0], k[0], acc);
        acc = fmaf(q[1], k[1], acc);
        acc = fmaf(q[2], k[2], acc);
        acc = fmaf(q[3], k[3], acc);
    }
    float score = acc * SCALE;
    if (lane >= vlen[b]) score = NEGBIG;

    float work = score;
    float tv[STAT_K];
    int   ti[STAT_K];
    #pragma unroll
    for (int j = 0; j < STAT_K; ++j) {
        float m = work;
        #pragma unroll
        for (int off = 32; off > 0; off >>= 1) m = fmaxf(m, __shfl_xor(m, off));
        unsigned long long ball = __ballot(work == m);
        int L = __ffsll(ball) - 1;     // lowest index wins ties
        tv[j] = m;
        ti[j] = L;
        if (lane == L) work = NINF;
    }

    float w[STAT_K];
    float Z = 0.f;
    #pragma unroll
    for (int j = 0; j < STAT_K; ++j) { w[j] = expf(tv[j] - tv[0]); Z += w[j]; }
    float invZ = 1.f / Z;

    if (lane < STAT_K) {
        float wv = w[lane] * invZ;
        int pid = bq * STAT_K + lane;
        sel_i[pid] = ti[lane];
        sel_w[pid] = wv;
        if (wv != 0.f) {                         // sw==0: exactly-zero contribution
            int s  = ti[lane];
            int bs = b * SN + s;
            int pos = atomicAdd(&cnt[bs], 1);
            list[bs * 512 + pos] = (bq & 511) | (lane << 16);
        } else {
            #pragma unroll
            for (int j = 0; j < TOK_K; ++j)      // never written downstream: zero
                pvw[(size_t)pid * TOK_K + j] = 0.f;
        }
    }
}

// ---------------------------------------------------------------------------
// K1 (fused): token scores + EXACT top-16 + softmax weights, all in registers.
// Selection per round: exact fp32 group-max (4-step shfl fmax), then exact
// lowest-t tie-break via 2 ballots + 1 shfl (lower 64 tokens beat upper;
// lowest lane in group field = lowest t since lane tx owns t=4tx..4tx+3).
// Identical selected multiset + weights to R15 (which passed at 2.44e-4).
// it-loop outer, 4 pids inner (ILP). exp hoisted out of the loop.
// ---------------------------------------------------------------------------
__global__ __launch_bounds__(256) void tok_score_sel(const float* __restrict__ qt,
                                                     const float* __restrict__ kT,
                                                     const int* __restrict__ cnt,
                                                     const int* __restrict__ list,
                                                     const float* __restrict__ sel_w,
                                                     int* __restrict__ pvt,
                                                     float* __restrict__ pvw)
{
    const int bin   = blockIdx.x & 511;
    const int chunk = blockIdx.x >> 9;   // 0..7
    const int b  = bin & 7;              // batch fast -> XCD spread
    const int s  = bin >> 3;
    const int bs = b * SN + s;
    const int nq = cnt[bs];
    const int q0 = chunk * 64;
    if (q0 >= nq) return;                // wave-uniform early out: safe

    const int tid  = threadIdx.x;
    const int tx   = tid & 15;           // token-cols
    const int ty   = tid >> 4;           // pair-slots q0+ty*4..+3
    const int lane = tid & 63;
    const int g    = lane >> 4;          // 16-lane group within wave

    int pid[4];
    float swp[4];
    const float* Ab[4];
    #pragma unroll
    for (int i = 0; i < 4; ++i) {
        int e  = list[bs * 512 + min(q0 + ty * 4 + i, nq - 1)];  // clamp: dup pair
        int q  = e & 0xffff;
        int si = (e >> 16) & 7;
        pid[i] = ((b << 9) + q) * 8 + si;
        swp[i] = sel_w[pid[i]];
        Ab[i]  = qt + ((size_t)(b << 9) + q) * 128;
    }
    const float* kb = kT + ((size_t)bs << 14);

    float acc[4][8];
    #pragma unroll
    for (int i = 0; i < 4; ++i)
        #pragma unroll
        for (int j = 0; j < 8; ++j) acc[i][j] = 0.f;

    #pragma unroll 2
    for (int k0 = 0; k0 < 128; k0 += 4) {
        f4 a[4];
        #pragma unroll
        for (int i = 0; i < 4; ++i)
            a[i] = *(const f4*)(Ab[i] + k0);               // 16-lane broadcast
        f4 wl[4], wh[4];
        #pragma unroll
        for (int kk = 0; kk < 4; ++kk) {
            wl[kk] = *(const f4*)(kb + (size_t)(k0 + kk) * 128 + tx * 4);
            wh[kk] = *(const f4*)(kb + (size_t)(k0 + kk) * 128 + 64 + tx * 4);
        }
        #pragma unroll
        for (int i = 0; i < 4; ++i)
            #pragma unroll
            for (int kk = 0; kk < 4; ++kk)
                #pragma unroll
                for (int j = 0; j < 4; ++j) {
                    acc[i][j]     = fmaf(a[i][kk], wl[kk][j], acc[i][j]);
                    acc[i][4 + j] = fmaf(a[i][kk], wh[kk][j], acc[i][4 + j]);
                }
    }

    // ---- exact in-register top-16 + softmax, 4 pids interleaved ----
    float s8[4][8];
    #pragma unroll
    for (int i = 0; i < 4; ++i)
        #pragma unroll
        for (int j = 0; j < 8; ++j) s8[i][j] = acc[i][j] * SCALE;

    float m0[4], myM[4];
    int   myT[4];
    #pragma unroll
    for (int i = 0; i < 4; ++i) { m0[i] = 0.f; myM[i] = 0.f; myT[i] = 0; }

    for (int it = 0; it < 16; ++it) {
        #pragma unroll
        for (int i = 0; i < 4; ++i) {
            // exact fp32 group max (tree + 4-step shfl, stays in 16-lane group)
            float v01 = fmaxf(s8[i][0], s8[i][1]);
            float v23 = fmaxf(s8[i][2], s8[i][3]);
            float v45 = fmaxf(s8[i][4], s8[i][5]);
            float v67 = fmaxf(s8[i][6], s8[i][7]);
            float m = fmaxf(fmaxf(v01, v23), fmaxf(v45, v67));
            #pragma unroll
            for (int off = 8; off > 0; off >>= 1) m = fmaxf(m, __shfl_xor(m, off));

            // per-lane lowest hit slot in each half (descending scan)
            int jlo = 4, jhi = 4;                     // 4 = no hit
            #pragma unroll
            for (int j = 3; j >= 0; --j) jlo = (s8[i][j]     == m) ? j : jlo;
            #pragma unroll
            for (int j = 3; j >= 0; --j) jhi = (s8[i][4 + j] == m) ? j : jhi;

            // exact lowest-t via ballots: lower half beats upper; lowest lane
            // = lowest t (lane tx owns t = 4tx..4tx+3 / 64+4tx..64+4tx+3)
            u64 blo = __ballot(jlo < 4);
            u64 bhi = __ballot(jhi < 4);
            unsigned mlo = (unsigned)((blo >> (g * 16)) & 0xFFFFu);
            unsigned mhi = (unsigned)((bhi >> (g * 16)) & 0xFFFFu);
            bool lo = (mlo != 0);
            unsigned msel = lo ? mlo : mhi;
            int L = __ffs(msel) - 1;                  // winner lane in group
            int jsel = lo ? jlo : jhi;
            int jwin = __shfl(jsel, g * 16 + L);      // winner's slot-in-half
            int tstar = (lo ? 0 : 64) + 4 * L + jwin;

            m0[i] = (it == 0) ? m : m0[i];
            bool rec = (tx == it);
            myT[i] = rec ? tstar : myT[i];
            myM[i] = rec ? m : myM[i];

            // branch-free knock of the unique winning slot
            int slot = (lo ? 0 : 4) + jwin;           // wave-uniform within group
            bool winlane = (tx == L);
            #pragma unroll
            for (int j = 0; j < 8; ++j)
                s8[i][j] = (winlane && slot == j) ? NINF : s8[i][j];
        }
    }

    #pragma unroll
    for (int i = 0; i < 4; ++i) {
        float myE = expf(myM[i] - m0[i]);      // exact, same as R15
        float Z = myE;
        #pragma unroll
        for (int off = 8; off > 0; off >>= 1) Z += __shfl_xor(Z, off);
        float cs = swp[i] / Z;                 // fold stat weight in

        pvt[(size_t)pid[i] * TOK_K + tx] = myT[i];   // dup pids: identical data
        pvw[(size_t)pid[i] * TOK_K + tx] = myE * cs;
    }
}

// ---------------------------------------------------------------------------
// K3 (fused): PV accumulate on RAW values + output projection with M_vo.
// One wave per (b,q): PV row in registers -> LDS (same-wave, in-order) ->
// row @ M_vo (L1-resident) -> direct store to d_out. Numerically identical
// to R15's pv2 + proj_out (same fma order). No atomics.
// t clamped to [0,127]: stale pvt for unbinned pids is harmless (pvw==0).
// ---------------------------------------------------------------------------
__global__ __launch_bounds__(256) void tok_pv3(const float* __restrict__ values,
                                               const int* __restrict__ sel_i,
                                               const int* __restrict__ pvt,
                                               const float* __restrict__ pvw,
                                               const float* __restrict__ M_vo,
                                               float* __restrict__ out)
{
    const int wid  = threadIdx.x >> 6;
    const int bq   = blockIdx.x * 4 + wid;
    const int lane = threadIdx.x & 63;
    const int b    = bq >> 9;

    float o0 = 0.f, o1 = 0.f;
    #pragma unroll
    for (int si = 0; si < STAT_K; ++si) {
        const int pid = bq * STAT_K + si;
        const int s   = sel_i[pid];
        const float* vb = values + ((size_t)(b * SN + s) << 14);
        const int*   tp = pvt + (size_t)pid * TOK_K;
        const float* wp = pvw + (size_t)pid * TOK_K;
        #pragma unroll
        for (int j = 0; j < TOK_K; ++j) {
            int   t = tp[j] & 127;           // wave-uniform; clamp stale entries
            float w = wp[j];                 // ==0 for skipped pids: exact no-op
            f2 x = *(const f2*)(vb + (size_t)t * 128 + lane * 2);
            o0 = fmaf(w, x[0], o0);
            o1 = fmaf(w, x[1], o1);
        }
    }

    __shared__ float pre[4][128];
    *(f2*)&pre[wid][lane * 2] = (f2){o0, o1};
    __asm__ __volatile__("" ::: "memory");
    __builtin_amdgcn_wave_barrier();        // same-wave LDS RAW: in-order pipe
    __asm__ __volatile__("" ::: "memory");

    float r0 = 0.f, r1 = 0.f;
    #pragma unroll 4
    for (int d = 0; d < 128; ++d) {
        float p = pre[wid][d];               // broadcast read
        f2 w = *(const f2*)(M_vo + (size_t)d * 128 + lane * 2);
        r0 = fmaf(p, w[0], r0);
        r1 = fmaf(p, w[1], r1);
    }
    *(f2*)&out[(size_t)bq * 128 + lane * 2] = (f2){r0, r1};
}

// ---------------------------------------------------------------------------
extern "C" void kernel_launch(void* const* d_in, const int* in_sizes, int n_in,
                              void* d_out, int out_size, void* d_ws, size_t ws_size,
                              hipStream_t stream)
{
    const float* queries    = (const float*)d_in[0];
    const float* stat_keys  = (const float*)d_in[1];
    const float* token_keys = (const float*)d_in[2];
    const float* values     = (const float*)d_in[3];
    const int*   vlen       = (const int*)d_in[4];
    const float* Wq_stat    = (const float*)d_in[5];
    const float* Wq_token   = (const float*)d_in[6];
    const float* Wk_stat    = (const float*)d_in[7];
    const float* Wk_token   = (const float*)d_in[8];
    const float* Wv         = (const float*)d_in[9];
    const float* Wo         = (const float*)d_in[10];

    char* ws = (char*)d_ws;
    float* q_stat  = (float*)(ws);                 // 2 MB
    float* q_tok   = (float*)(ws + 2097152);       // 2 MB
    float* k_stat  = (float*)(ws + 4194304);       // 256 KB
    float* M_vo    = (float*)(ws + 4456448);       // 64 KB (Wv @ Wo)
    int*   sel_i   = (int*)  (ws + 4521984);       // 128 KB
    float* sel_w   = (float*)(ws + 4653056);       // 128 KB
    float* kT      = (float*)(ws + 4784128);       // 32 MB
    int*   pvt     = (int*)  (ws + 38338560);      // 2 MB
    float* pvw     = (float*)(ws + 40435712);      // 2 MB
    int*   list    = (int*)  (ws + 42532864);      // 1 MB
    int*   cnt     = (int*)  (ws + 43581440);      // 2 KB   (total ~43.6 MB)

    // Projections feeding selection (fp32 exact) + Wv@Wo fold + cnt zeroing
    proj_all<<<1163, 256, 0, stream>>>(queries, stat_keys, token_keys,
                                       Wq_stat, Wq_token, Wk_stat, Wk_token, Wv, Wo,
                                       q_stat, q_tok, k_stat, kT, M_vo, cnt);

    // Stat-level top-8 + weights + bin append + pvw zeroing (fused)
    stat_topk<<<BB * QN, 64, 0, stream>>>(q_stat, k_stat, vlen, sel_i, sel_w,
                                          cnt, list, pvw);

    // K1: token scores + exact in-register top-16 + weights (no scores buffer)
    tok_score_sel<<<4096, 256, 0, stream>>>(q_tok, kT, cnt, list, sel_w, pvt, pvw);

    // K3: PV + output projection fused, one wave per (b,q), direct to d_out
    tok_pv3<<<BB * QN / 4, 256, 0, stream>>>(values, sel_i, pvt, pvw, M_vo,
                                             (float*)d_out);
}